// Round 9
// baseline (375.440 us; speedup 1.0000x reference)
//
#include <hip/hip_runtime.h>
#include <math.h>

static constexpr int KNN = 40;

__device__ __forceinline__ float lrelu_f(float v){ return v >= 0.f ? v : 0.5f*v; }

// padded-weight workspace offsets (floats)
#define PAD_OFF_GWS   0        // 12x16   (gWs, 8 cols)
#define PAD_OFF_GWH   192      // 12x32   (gWh, 22 cols)
#define PAD_OFF_N1W2  576      // 64x16   (n1W2, 12 cols)
#define PAD_OFF_N2W0  1600     // 64x128  (n2W0, 126 cols)
#define PAD_OFF_N2W1  9792     // 126x128
#define PAD_OFF_N2W2  25920    // 126x128
#define PAD_OFF_N2W3  42048    // 126x16  (6 cols)
#define PAD_OFF_N3W0  44064    // 82x128
#define PAD_OFF_N3W1  54560    // 126x128
#define PAD_OFF_N3W2  70688    // 126x128
#define PAD_OFF_N3W3  86816    // 126x16  (6 cols)
#define PAD_TOTAL     88832

__global__ void pad_weights(const float* gWs,const float* gWh,const float* n1W2,
                            const float* n2W0,const float* n2W1,const float* n2W2,const float* n2W3,
                            const float* n3W0,const float* n3W1,const float* n3W2,const float* n3W3,
                            float* __restrict__ wp)
{
    int i = blockIdx.x*blockDim.x + threadIdx.x;
    if (i >= PAD_TOTAL) return;
    const float* src; int cols, sh, off;
    if      (i < PAD_OFF_GWH)  { src=gWs;  cols=8;   sh=4; off=PAD_OFF_GWS;  }
    else if (i < PAD_OFF_N1W2) { src=gWh;  cols=22;  sh=5; off=PAD_OFF_GWH;  }
    else if (i < PAD_OFF_N2W0) { src=n1W2; cols=12;  sh=4; off=PAD_OFF_N1W2; }
    else if (i < PAD_OFF_N2W1) { src=n2W0; cols=126; sh=7; off=PAD_OFF_N2W0; }
    else if (i < PAD_OFF_N2W2) { src=n2W1; cols=126; sh=7; off=PAD_OFF_N2W1; }
    else if (i < PAD_OFF_N2W3) { src=n2W2; cols=126; sh=7; off=PAD_OFF_N2W2; }
    else if (i < PAD_OFF_N3W0) { src=n2W3; cols=6;   sh=4; off=PAD_OFF_N2W3; }
    else if (i < PAD_OFF_N3W1) { src=n3W0; cols=126; sh=7; off=PAD_OFF_N3W0; }
    else if (i < PAD_OFF_N3W2) { src=n3W1; cols=126; sh=7; off=PAD_OFF_N3W1; }
    else if (i < PAD_OFF_N3W3) { src=n3W2; cols=126; sh=7; off=PAD_OFF_N3W2; }
    else                       { src=n3W3; cols=6;   sh=4; off=PAD_OFF_N3W3; }
    int li = i - off;
    int r = li >> sh, c = li & ((1<<sh)-1);
    wp[i] = (c < cols) ? src[r*cols + c] : 0.f;
}

// ---- lin32: 32 rows per block (r = tid&31), col-group (tid>>5)*8. ----
// W pitch WPITCH (multiple of 4), readable/zero-padded up to ceil8(NOUT) cols.
template<int K, int NOUT, int WPITCH, bool RELU, int NTH>
__device__ __forceinline__
void lin32(const float* __restrict__ Xs, int xpitch,
           const float* __restrict__ W, const float* __restrict__ Bv,
           float* __restrict__ Y, int ypitch, int tid)
{
    constexpr int NP  = ((NOUT+7)/8)*8;
    constexpr int NCG = NP/8;
    constexpr int NG  = NTH/32;
    const int r = tid & 31;
    for (int cg = tid >> 5; cg < NCG; cg += NG) {
        float acc[8];
        #pragma unroll
        for (int j=0;j<8;++j){ int c=cg*8+j; acc[j] = (c < NOUT) ? Bv[c] : 0.f; }
        const float* xrow = &Xs[(long)r*xpitch];
        const float* wp = &W[cg*8];
        #pragma unroll 4
        for (int k=0;k<K;++k){
            const float xv = xrow[k];
            const float4* w4 = reinterpret_cast<const float4*>(wp + (long)k*WPITCH);
            float4 a = w4[0], b = w4[1];
            acc[0]=fmaf(xv,a.x,acc[0]); acc[1]=fmaf(xv,a.y,acc[1]);
            acc[2]=fmaf(xv,a.z,acc[2]); acc[3]=fmaf(xv,a.w,acc[3]);
            acc[4]=fmaf(xv,b.x,acc[4]); acc[5]=fmaf(xv,b.y,acc[5]);
            acc[6]=fmaf(xv,b.z,acc[6]); acc[7]=fmaf(xv,b.w,acc[7]);
        }
        #pragma unroll
        for (int j=0;j<8;++j){
            int c = cg*8 + j;
            if (c < NOUT){ float v = acc[j]; if (RELU) v = lrelu_f(v); Y[(long)r*ypitch + c] = v; }
        }
    }
    __syncthreads();
}

template<int K, int NOUT, int WPITCH, int NTH>
__device__ __forceinline__
void lin32_dual(const float* __restrict__ Xs, int xp, const float* __restrict__ X2s, int xp2,
                const float* __restrict__ W, const float* __restrict__ Bv, const float* __restrict__ W2,
                float* __restrict__ Y, int ypitch, int tid)
{
    constexpr int NP  = ((NOUT+7)/8)*8;
    constexpr int NCG = NP/8;
    constexpr int NG  = NTH/32;
    const int r = tid & 31;
    for (int cg = tid >> 5; cg < NCG; cg += NG) {
        float acc[8];
        #pragma unroll
        for (int j=0;j<8;++j){ int c=cg*8+j; acc[j] = (c < NOUT) ? Bv[c] : 0.f; }
        {
            const float* xrow = &Xs[(long)r*xp];
            const float* wp = &W[cg*8];
            #pragma unroll 4
            for (int k=0;k<K;++k){
                const float xv = xrow[k];
                const float4* w4 = reinterpret_cast<const float4*>(wp + (long)k*WPITCH);
                float4 a = w4[0], b = w4[1];
                acc[0]=fmaf(xv,a.x,acc[0]); acc[1]=fmaf(xv,a.y,acc[1]);
                acc[2]=fmaf(xv,a.z,acc[2]); acc[3]=fmaf(xv,a.w,acc[3]);
                acc[4]=fmaf(xv,b.x,acc[4]); acc[5]=fmaf(xv,b.y,acc[5]);
                acc[6]=fmaf(xv,b.z,acc[6]); acc[7]=fmaf(xv,b.w,acc[7]);
            }
        }
        {
            const float* xrow = &X2s[(long)r*xp2];
            const float* wp = &W2[cg*8];
            #pragma unroll 4
            for (int k=0;k<K;++k){
                const float xv = xrow[k];
                const float4* w4 = reinterpret_cast<const float4*>(wp + (long)k*WPITCH);
                float4 a = w4[0], b = w4[1];
                acc[0]=fmaf(xv,a.x,acc[0]); acc[1]=fmaf(xv,a.y,acc[1]);
                acc[2]=fmaf(xv,a.z,acc[2]); acc[3]=fmaf(xv,a.w,acc[3]);
                acc[4]=fmaf(xv,b.x,acc[4]); acc[5]=fmaf(xv,b.y,acc[5]);
                acc[6]=fmaf(xv,b.z,acc[6]); acc[7]=fmaf(xv,b.w,acc[7]);
            }
        }
        #pragma unroll
        for (int j=0;j<8;++j){
            int c = cg*8 + j;
            if (c < NOUT) Y[(long)r*ypitch + c] = acc[j];
        }
    }
    __syncthreads();
}

// final 126->6 layer, 32 rows: one output per thread (192 active), W pitch 16
template<int K, int NTH>
__device__ __forceinline__
void lin_out6_32(const float* __restrict__ Xs, int xpitch,
                 const float* __restrict__ Wp, const float* __restrict__ Bv,
                 float* __restrict__ Y, int ypitch, int tid)
{
    if (tid < 32*6) {
        const int r = tid / 6, c = tid - r*6;
        float acc = Bv[c];
        const float* xrow = &Xs[(long)r*xpitch];
        #pragma unroll 4
        for (int k=0;k<K;++k) acc = fmaf(xrow[k], Wp[k*16+c], acc);
        Y[(long)r*ypitch + c] = lrelu_f(acc);
    }
    __syncthreads();
}

// ---------------- F1: nn1 encoder + gWs + gWh + |s|^2 (32 rows/block) ----------------
__global__ __launch_bounds__(256)
void f1_encoder(const float* __restrict__ x0, const float* __restrict__ wp,
                const float* n1W0,const float* n1b0,const float* n1W1,const float* n1b1,
                const float* n1b2, const float* gbs, const float* gbh,
                float* __restrict__ x12g, float* __restrict__ sg,
                float* __restrict__ sqg, float* __restrict__ hg /*pitch 32*/)
{
    __shared__ float A1[32*65], A2[32*65], Ss[32*9];
    const int tid = threadIdx.x;
    const long row0 = (long)blockIdx.x*32;
    lin32<12,64,64,true,256>(x0+row0*12,12, n1W0, n1b0, A1,65, tid);
    lin32<64,64,64,true,256>(A1,65, n1W1, n1b1, A2,65, tid);
    lin32<64,12,16,true,256>(A2,65, wp+PAD_OFF_N1W2, n1b2, A1,13, tid);
    for (int i=tid;i<32*12;i+=256){ int r=i/12,c=i-r*12; x12g[(row0+r)*12+c]=A1[r*13+c]; }
    lin32<12,8,16,false,256>(A1,13, wp+PAD_OFF_GWS, gbs, Ss,9, tid);
    lin32<12,22,32,false,256>(A1,13, wp+PAD_OFF_GWH, gbh, hg+row0*32,32, tid);
    if (tid < 32) {
        float acc = 0.f;
        #pragma unroll
        for (int k=0;k<8;++k){ float v=Ss[tid*9+k]; sg[(row0+tid)*8+k]=v; acc=fmaf(v,v,acc); }
        sqg[row0+tid] = acc;
    }
}

// ---------------- kNN: 4 q/wave, 4 cand/lane, sorted-pair top-2, dbuf tiles ----------------
template<int C>
__device__ __forceinline__ unsigned dpp_umin(unsigned x){
    unsigned y = (unsigned)__builtin_amdgcn_update_dpp((int)x, (int)x, C, 0xf, 0xf, false);
    return x < y ? x : y;
}
__device__ __forceinline__ unsigned wave_umin64(unsigned x){
    x = dpp_umin<0x111>(x);
    x = dpp_umin<0x112>(x);
    x = dpp_umin<0x114>(x);
    x = dpp_umin<0x118>(x);
    x = dpp_umin<0x142>(x);
    x = dpp_umin<0x143>(x);
    return x;   // lane 63 holds the wave min
}

#define KNN_WPB 4
#define QPW 4

__global__ __launch_bounds__(256)
void knn_kernel(const float* __restrict__ S, const float* __restrict__ SQ,
                int* __restrict__ idx_out, float* __restrict__ w_out, int N)
{
    __shared__ __align__(16) float tile[2][9*256];
    const int tid  = threadIdx.x;
    const int lane = tid & 63;
    const int wv   = tid >> 6;
    const int q0   = (blockIdx.x*KNN_WPB + wv)*QPW;
    const int qtile = q0 >> 8;

    float qa[QPW][8]; float sqq[QPW];
    #pragma unroll
    for (int qq=0; qq<QPW; ++qq) {
        const float4* qp = reinterpret_cast<const float4*>(&S[(long)(q0+qq)*8]);
        float4 a = qp[0], b = qp[1];
        qa[qq][0]=a.x; qa[qq][1]=a.y; qa[qq][2]=a.z; qa[qq][3]=a.w;
        qa[qq][4]=b.x; qa[qq][5]=b.y; qa[qq][6]=b.z; qa[qq][7]=b.w;
        sqq[qq] = SQ[q0+qq];
    }

    unsigned s0[QPW], s1[QPW];
    #pragma unroll
    for (int qq=0; qq<QPW; ++qq){ s0[qq]=0xFFFFFFFFu; s1[qq]=0xFFFFFFFFu; }

    const int NT = N >> 8;
    {   // prologue: stage tile 0
        const float4* cp = reinterpret_cast<const float4*>(&S[(long)tid*8]);
        float4 a = cp[0], b = cp[1];
        float* tl = &tile[0][0];
        tl[0*256+tid]=a.x; tl[1*256+tid]=a.y; tl[2*256+tid]=a.z; tl[3*256+tid]=a.w;
        tl[4*256+tid]=b.x; tl[5*256+tid]=b.y; tl[6*256+tid]=b.z; tl[7*256+tid]=b.w;
        tl[8*256+tid]=SQ[tid];
    }
    #pragma unroll 1
    for (int t = 0; t < NT; ++t) {
        __syncthreads();   // tile[t&1] ready; alt buffer free
        if (t+1 < NT) {
            const int c = (t+1)*256 + tid;
            const float4* cp = reinterpret_cast<const float4*>(&S[(long)c*8]);
            float4 a = cp[0], b = cp[1];
            float* tl = &tile[(t+1)&1][0];
            tl[0*256+tid]=a.x; tl[1*256+tid]=a.y; tl[2*256+tid]=a.z; tl[3*256+tid]=a.w;
            tl[4*256+tid]=b.x; tl[5*256+tid]=b.y; tl[6*256+tid]=b.z; tl[7*256+tid]=b.w;
            tl[8*256+tid]=SQ[c];
        }
        const float* tl = &tile[t&1][0];

        float dot[QPW][4];
        #pragma unroll
        for (int qq=0;qq<QPW;++qq){ dot[qq][0]=0.f; dot[qq][1]=0.f; dot[qq][2]=0.f; dot[qq][3]=0.f; }
        #pragma unroll
        for (int k=0;k<8;++k){
            float4 v = *reinterpret_cast<const float4*>(&tl[k*256 + lane*4]);
            #pragma unroll
            for (int qq=0;qq<QPW;++qq){
                dot[qq][0] = fmaf(qa[qq][k], v.x, dot[qq][0]);
                dot[qq][1] = fmaf(qa[qq][k], v.y, dot[qq][1]);
                dot[qq][2] = fmaf(qa[qq][k], v.z, dot[qq][2]);
                dot[qq][3] = fmaf(qa[qq][k], v.w, dot[qq][3]);
            }
        }
        float4 sc = *reinterpret_cast<const float4*>(&tl[8*256 + lane*4]);
        const float scv[4] = {sc.x, sc.y, sc.z, sc.w};

        if (t != qtile) {
            #pragma unroll
            for (int qq=0;qq<QPW;++qq){
                #pragma unroll
                for (int i=0;i<4;++i){
                    float d2 = fmaf(-2.f, dot[qq][i], sqq[qq] + scv[i]);
                    d2 = fmaxf(d2, 0.f);
                    unsigned key = (__float_as_uint(d2) & 0xFFFFFF00u) | (unsigned)((t<<2)|i);
                    unsigned lo = s0[qq] < key ? s0[qq] : key;
                    unsigned hi = s0[qq] > key ? s0[qq] : key;
                    s0[qq] = lo;
                    s1[qq] = s1[qq] < hi ? s1[qq] : hi;
                }
            }
        } else {
            #pragma unroll
            for (int qq=0;qq<QPW;++qq){
                const int off = (q0+qq) - t*256;
                #pragma unroll
                for (int i=0;i<4;++i){
                    float d2 = fmaf(-2.f, dot[qq][i], sqq[qq] + scv[i]);
                    d2 = fmaxf(d2, 0.f);
                    unsigned key = (__float_as_uint(d2) & 0xFFFFFF00u) | (unsigned)((t<<2)|i);
                    if (lane*4 + i == off) key = 0xFFFFFFFFu;
                    unsigned lo = s0[qq] < key ? s0[qq] : key;
                    unsigned hi = s0[qq] > key ? s0[qq] : key;
                    s0[qq] = lo;
                    s1[qq] = s1[qq] < hi ? s1[qq] : hi;
                }
            }
        }
    }

    #pragma unroll
    for (int qq=0; qq<QPW; ++qq) {
        const int q = q0 + qq;
        unsigned savedK = 0; int savedC = 0;
        #pragma unroll 1
        for (int p=0; p<KNN; ++p) {
            unsigned red = wave_umin64(s0[qq]);
            unsigned gm = (unsigned)__builtin_amdgcn_readlane((int)red, 63);
            unsigned long long bal = __ballot(s0[qq] == gm);
            int owner = __ffsll((long long)bal) - 1;
            if (lane == owner) { s0[qq] = s1[qq]; s1[qq] = 0xFFFFFFFFu; }
            if (lane == p) { savedK = gm; savedC = owner; }
        }
        if (lane < KNN) {
            const int tl = (int)((savedK >> 2) & 0x3Fu);
            const int ii = (int)(savedK & 3u);
            const int c  = tl*256 + savedC*4 + ii;
            const float d2 = __uint_as_float(savedK & 0xFFFFFF00u);
            idx_out[(long)q*KNN + lane] = c;
            w_out[(long)q*KNN + lane]   = expf(-10.f * d2);
        }
    }
}

// ---------------- F2: GravNet aggregate + lin 56->64 (32 rows/block) ----------------
__global__ __launch_bounds__(256)
void f2_agg(const float* __restrict__ hg /*pitch 32*/, const int* __restrict__ idx,
            const float* __restrict__ wgt, const float* __restrict__ x12g,
            const float* gWo, const float* gbo, float* __restrict__ xg)
{
    __shared__ int   IDs[32*40];
    __shared__ float Wt[32*40];
    __shared__ float AGG[32*57];
    const int tid = threadIdx.x;
    const long row0 = (long)blockIdx.x*32;
    for (int i=tid;i<32*40;i+=256){ int r=i/40,k=i-r*40;
        IDs[i]=idx[(row0+r)*40+k]; Wt[i]=wgt[(row0+r)*40+k]; }
    for (int i=tid;i<32*12;i+=256){ int r=i/12,c=i-r*12; AGG[r*57+44+c]=x12g[(row0+r)*12+c]; }
    __syncthreads();
    {
        const int r = tid & 31, g = tid >> 5;   // g in 0..7, feats f0 = g*4
        const int f0 = g*4;
        const int nf = (f0 < 22) ? ((22-f0) < 4 ? (22-f0) : 4) : 0;
        float sm[4], mx[4];
        #pragma unroll
        for (int u=0;u<4;++u){ sm[u]=0.f; mx[u]=-INFINITY; }
        if (nf > 0) {
            #pragma unroll 1
            for (int k=0;k<40;++k){
                int j = IDs[r*40+k]; float wv = Wt[r*40+k];
                float4 h0 = *reinterpret_cast<const float4*>(&hg[(long)j*32 + f0]);
                float hv[4] = {h0.x,h0.y,h0.z,h0.w};
                #pragma unroll
                for (int u=0;u<4;++u){ float m = hv[u]*wv; sm[u]+=m; mx[u]=fmaxf(mx[u],m); }
            }
            #pragma unroll
            for (int u=0;u<4;++u) if (u<nf){ AGG[r*57+f0+u]=sm[u]*(1.f/40.f); AGG[r*57+22+f0+u]=mx[u]; }
        }
    }
    __syncthreads();
    lin32<56,64,64,false,256>(AGG,57, gWo, gbo, xg+row0*64,64, tid);
}

// ---------------- F3: GraphConv gather + dual linear (32 rows/block) ----------------
__global__ __launch_bounds__(256)
void f3_graphconv(const float* __restrict__ xgin, const int* __restrict__ idx,
                  const float* __restrict__ wgt,
                  const float* c2Wrel, const float* c2brel, const float* c2Wroot,
                  float* __restrict__ xc)
{
    __shared__ int   IDs[32*40];
    __shared__ float Wt[32*40];
    __shared__ float NB[32*65], XGs[32*65];
    const int tid = threadIdx.x;
    const long row0 = (long)blockIdx.x*32;
    for (int i=tid;i<32*40;i+=256){ int r=i/40,k=i-r*40;
        IDs[i]=idx[(row0+r)*40+k]; Wt[i]=wgt[(row0+r)*40+k]; }
    for (int i=tid;i<32*64;i+=256){ int r=i>>6,c=i&63; XGs[r*65+c]=xgin[(row0+r)*64+c]; }
    __syncthreads();
    {
        const int r = tid & 31, g = tid >> 5;   // g in 0..7, cols [8g,8g+8)
        float acc[8];
        #pragma unroll
        for (int j=0;j<8;++j) acc[j]=0.f;
        #pragma unroll 1
        for (int k=0;k<40;++k){
            int j = IDs[r*40+k]; float wv = Wt[r*40+k];
            const float4* xp = reinterpret_cast<const float4*>(&xgin[(long)j*64 + g*8]);
            float4 v0 = xp[0], v1 = xp[1];
            acc[0]=fmaf(v0.x,wv,acc[0]); acc[1]=fmaf(v0.y,wv,acc[1]);
            acc[2]=fmaf(v0.z,wv,acc[2]); acc[3]=fmaf(v0.w,wv,acc[3]);
            acc[4]=fmaf(v1.x,wv,acc[4]); acc[5]=fmaf(v1.y,wv,acc[5]);
            acc[6]=fmaf(v1.z,wv,acc[6]); acc[7]=fmaf(v1.w,wv,acc[7]);
        }
        #pragma unroll
        for (int j=0;j<8;++j) NB[r*65 + g*8 + j] = acc[j];
    }
    __syncthreads();
    lin32_dual<64,64,64,256>(NB,65, XGs,65, c2Wrel,c2brel,c2Wroot, xc+row0*64,64, tid);
}

// ---------------- F45: nn2 head + concat + nn3 head (32 rows, 512 threads) ----------------
__global__ __launch_bounds__(512)
void f45_heads(const float* __restrict__ xc, const float* __restrict__ x0,
               const float* __restrict__ wp,
               const float* A_b0,const float* A_b1,const float* A_b2,const float* A_b3,
               const float* B_b0,const float* B_b1,const float* B_b2,const float* B_b3,
               float* __restrict__ outIds, float* __restrict__ outP4)
{
    __shared__ float A0[32*127], A1[32*127], IDS[32*6];
    const int tid = threadIdx.x;
    const long row0 = (long)blockIdx.x*32;
    // ---- nn2 ----
    for (int i=tid;i<32*64;i+=512){ int r=i>>6,c=i&63; A0[r*127+c]=xc[(row0+r)*64+c]; }
    __syncthreads();
    lin32<64,126,128,true,512>(A0,127, wp+PAD_OFF_N2W0, A_b0, A1,127, tid);
    lin32<126,126,128,true,512>(A1,127, wp+PAD_OFF_N2W1, A_b1, A0,127, tid);
    lin32<126,126,128,true,512>(A0,127, wp+PAD_OFF_N2W2, A_b2, A1,127, tid);
    lin_out6_32<126,512>(A1,127, wp+PAD_OFF_N2W3, A_b3, IDS,6, tid);
    for (int i=tid;i<32*6;i+=512){ int r=i/6,c=i-r*6; outIds[(row0+r)*6+c]=IDS[i]; }
    // ---- concat [xc, ids, x0] -> 82 ----
    for (int i=tid;i<32*64;i+=512){ int r=i>>6,c=i&63; A0[r*127+c]=xc[(row0+r)*64+c]; }
    for (int i=tid;i<32*6;i+=512){ int r=i/6,c=i-r*6; A0[r*127+64+c]=IDS[i]; }
    for (int i=tid;i<32*12;i+=512){ int r=i/12,c=i-r*12; A0[r*127+70+c]=x0[(row0+r)*12+c]; }
    __syncthreads();
    // ---- nn3 ----
    lin32<82,126,128,true,512>(A0,127, wp+PAD_OFF_N3W0, B_b0, A1,127, tid);
    lin32<126,126,128,true,512>(A1,127, wp+PAD_OFF_N3W1, B_b1, A0,127, tid);
    lin32<126,126,128,true,512>(A0,127, wp+PAD_OFF_N3W2, B_b2, A1,127, tid);
    lin_out6_32<126,512>(A1,127, wp+PAD_OFF_N3W3, B_b3, outP4+row0*6,6, tid);
}

// ---------------- passthrough outputs ----------------
__global__ void copyout_kernel(const int* __restrict__ gid, const float* __restrict__ gy,
                               const int* __restrict__ cid, const float* __restrict__ cy,
                               float* __restrict__ out, int N)
{
    long i = (long)blockIdx.x*blockDim.x + threadIdx.x;
    long n = N;
    if (i < n)            out[12*n + i]         = (float)gid[i];
    else if (i < 7*n)     out[13*n + (i - n)]   = gy[i - n];
    else if (i < 8*n)     out[19*n + (i - 7*n)] = (float)cid[i - 7*n];
    else if (i < 14*n)    out[20*n + (i - 8*n)] = cy[i - 8*n];
}

extern "C" void kernel_launch(void* const* d_in, const int* in_sizes, int n_in,
                              void* d_out, int out_size, void* d_ws, size_t ws_size,
                              hipStream_t stream)
{
    const float* x0     = (const float*)d_in[0];
    const float* ygen   = (const float*)d_in[1];
    const float* ycand  = (const float*)d_in[2];
    const int*   ygenid = (const int*)d_in[3];
    const int*   ycandid= (const int*)d_in[4];
    const float* n1W0=(const float*)d_in[5],  *n1b0=(const float*)d_in[6];
    const float* n1W1=(const float*)d_in[7],  *n1b1=(const float*)d_in[8];
    const float* n1W2=(const float*)d_in[9],  *n1b2=(const float*)d_in[10];
    const float* gWs =(const float*)d_in[11], *gbs =(const float*)d_in[12];
    const float* gWh =(const float*)d_in[13], *gbh =(const float*)d_in[14];
    const float* gWo =(const float*)d_in[15], *gbo =(const float*)d_in[16];
    const float* c2Wrel=(const float*)d_in[17], *c2brel=(const float*)d_in[18];
    const float* c2Wroot=(const float*)d_in[19];
    const float* n2W0=(const float*)d_in[20], *n2b0=(const float*)d_in[21];
    const float* n2W1=(const float*)d_in[22], *n2b1=(const float*)d_in[23];
    const float* n2W2=(const float*)d_in[24], *n2b2=(const float*)d_in[25];
    const float* n2W3=(const float*)d_in[26], *n2b3=(const float*)d_in[27];
    const float* n3W0=(const float*)d_in[28], *n3b0=(const float*)d_in[29];
    const float* n3W1=(const float*)d_in[30], *n3b1=(const float*)d_in[31];
    const float* n3W2=(const float*)d_in[32], *n3b2=(const float*)d_in[33];
    const float* n3W3=(const float*)d_in[34], *n3b3=(const float*)d_in[35];

    const int N = in_sizes[0] / 12;      // 16384
    float* ws = (float*)d_ws;
    size_t off = 0;
    auto alloc = [&](size_t cnt){ float* p = ws + off; off += cnt; return p; };
    float* padw = alloc(PAD_TOTAL);
    float* x12  = alloc((size_t)N*12);
    float* s    = alloc((size_t)N*8);
    float* sq   = alloc((size_t)N);
    float* h    = alloc((size_t)N*32);
    int*   idxb = (int*)alloc((size_t)N*KNN);
    float* wb   = alloc((size_t)N*KNN);
    float* xg   = alloc((size_t)N*64);
    float* xc   = alloc((size_t)N*64);
    (void)ws_size; (void)n_in; (void)out_size;

    float* outF = (float*)d_out;
    const int GB32 = N / 32;             // 512 blocks

    pad_weights<<<(PAD_TOTAL+255)/256,256,0,stream>>>(gWs,gWh,n1W2,
                                                      n2W0,n2W1,n2W2,n2W3,
                                                      n3W0,n3W1,n3W2,n3W3, padw);
    f1_encoder<<<GB32,256,0,stream>>>(x0, padw, n1W0,n1b0, n1W1,n1b1, n1b2,
                                      gbs, gbh, x12, s, sq, h);
    knn_kernel<<<N/(KNN_WPB*QPW), 256, 0, stream>>>(s, sq, idxb, wb, N);
    f2_agg<<<GB32,256,0,stream>>>(h, idxb, wb, x12, gWo, gbo, xg);
    f3_graphconv<<<GB32,256,0,stream>>>(xg, idxb, wb, c2Wrel, c2brel, c2Wroot, xc);
    f45_heads<<<GB32,512,0,stream>>>(xc, x0, padw,
                                     n2b0,n2b1,n2b2,n2b3, n3b0,n3b1,n3b2,n3b3,
                                     outF, outF + (size_t)N*6);
    copyout_kernel<<<(14*N+255)/256,256,0,stream>>>(ygenid, ygen, ycandid, ycand, outF, N);
}

// Round 10
// 291.501 us; speedup vs baseline: 1.2880x; 1.2880x over previous
//
#include <hip/hip_runtime.h>
#include <math.h>

static constexpr int KNN = 40;

__device__ __forceinline__ float lrelu_f(float v){ return v >= 0.f ? v : 0.5f*v; }

typedef _Float16 half8 __attribute__((ext_vector_type(8)));
typedef float    f32x4 __attribute__((ext_vector_type(4)));

// ---- fp32 padded-weight offsets (floats) ----
#define PAD_OFF_GWS   0        // 12x16  (8 cols)
#define PAD_OFF_GWH   192      // 12x32  (22 cols)
#define PAD_OFF_N1W2  576      // 64x16  (12 cols)
#define PAD_OFF_N2W3  1600     // 126x16 (6 cols)
#define PAD_OFF_N3W3  3616     // 126x16 (6 cols)
#define PAD_TOTAL     5632

// ---- fp16 transposed weight offsets (halves): WT[n][k], n padded to 128 ----
#define T_N2W0  0        // KP=64  (K=64)
#define T_N2W1  8192     // KP=128 (K=126)
#define T_N2W2  24576    // KP=128
#define T_N3W0  40960    // KP=96  (K=82)
#define T_N3W1  53248    // KP=128
#define T_N3W2  69632    // KP=128
#define T_TOTAL 86016

__global__ void pad_weights(const float* gWs,const float* gWh,const float* n1W2,
                            const float* n2W3,const float* n3W3,
                            float* __restrict__ wp)
{
    int i = blockIdx.x*blockDim.x + threadIdx.x;
    if (i >= PAD_TOTAL) return;
    const float* src; int cols, sh, off;
    if      (i < PAD_OFF_GWH)  { src=gWs;  cols=8;  sh=4; off=PAD_OFF_GWS;  }
    else if (i < PAD_OFF_N1W2) { src=gWh;  cols=22; sh=5; off=PAD_OFF_GWH;  }
    else if (i < PAD_OFF_N2W3) { src=n1W2; cols=12; sh=4; off=PAD_OFF_N1W2; }
    else if (i < PAD_OFF_N3W3) { src=n2W3; cols=6;  sh=4; off=PAD_OFF_N2W3; }
    else                       { src=n3W3; cols=6;  sh=4; off=PAD_OFF_N3W3; }
    int li = i - off;
    int r = li >> sh, c = li & ((1<<sh)-1);
    wp[i] = (c < cols) ? src[r*cols + c] : 0.f;
}

__global__ void pad_weights16(const float* n2W0,const float* n2W1,const float* n2W2,
                              const float* n3W0,const float* n3W1,const float* n3W2,
                              _Float16* __restrict__ wt)
{
    int i = blockIdx.x*blockDim.x + threadIdx.x;
    if (i >= T_TOTAL) return;
    const float* src; int KP, K, off;
    if      (i < T_N2W1) { src=n2W0; KP=64;  K=64;  off=T_N2W0; }
    else if (i < T_N2W2) { src=n2W1; KP=128; K=126; off=T_N2W1; }
    else if (i < T_N3W0) { src=n2W2; KP=128; K=126; off=T_N2W2; }
    else if (i < T_N3W1) { src=n3W0; KP=96;  K=82;  off=T_N3W0; }
    else if (i < T_N3W2) { src=n3W1; KP=128; K=126; off=T_N3W1; }
    else                 { src=n3W2; KP=128; K=126; off=T_N3W2; }
    int li = i - off;
    int n = li / KP, k = li - n*KP;
    float v = (n < 126 && k < K) ? src[k*126 + n] : 0.f;
    wt[i] = (_Float16)v;
}

// ---- lin8 (R8): wave owns 8 output cols -> wave-uniform W addresses ----
template<int K, int NOUT, int WPITCH, bool RELU, int NTH>
__device__ __forceinline__
void lin8(const float* __restrict__ Xs, int xpitch,
          const float* __restrict__ W, const float* __restrict__ Bv,
          float* __restrict__ Y, int ypitch, int tid)
{
    constexpr int NP  = ((NOUT+7)/8)*8;
    constexpr int NCG = NP/8;
    constexpr int NW  = NTH/64;
    const int lane = tid & 63;
    for (int g0 = tid >> 6; g0 < NCG; g0 += NW) {
        const int cg = __builtin_amdgcn_readfirstlane(g0);
        float acc[8];
        #pragma unroll
        for (int j=0;j<8;++j){ int c=cg*8+j; acc[j] = (c < NOUT) ? Bv[c] : 0.f; }
        const float* xrow = &Xs[(long)lane*xpitch];
        const float* wp = &W[cg*8];
        #pragma unroll 4
        for (int k=0;k<K;++k){
            const float xv = xrow[k];
            const float4* w4 = reinterpret_cast<const float4*>(wp + (long)k*WPITCH);
            float4 a = w4[0], b = w4[1];
            acc[0]=fmaf(xv,a.x,acc[0]); acc[1]=fmaf(xv,a.y,acc[1]);
            acc[2]=fmaf(xv,a.z,acc[2]); acc[3]=fmaf(xv,a.w,acc[3]);
            acc[4]=fmaf(xv,b.x,acc[4]); acc[5]=fmaf(xv,b.y,acc[5]);
            acc[6]=fmaf(xv,b.z,acc[6]); acc[7]=fmaf(xv,b.w,acc[7]);
        }
        #pragma unroll
        for (int j=0;j<8;++j){
            int c = cg*8 + j;
            if (c < NOUT){ float v = acc[j]; if (RELU) v = lrelu_f(v); Y[(long)lane*ypitch + c] = v; }
        }
    }
    __syncthreads();
}

template<int K, int NOUT, int WPITCH, int NTH>
__device__ __forceinline__
void lin8_dual(const float* __restrict__ Xs, int xp, const float* __restrict__ X2s, int xp2,
               const float* __restrict__ W, const float* __restrict__ Bv, const float* __restrict__ W2,
               float* __restrict__ Y, int ypitch, int tid)
{
    constexpr int NP  = ((NOUT+7)/8)*8;
    constexpr int NCG = NP/8;
    constexpr int NW  = NTH/64;
    const int lane = tid & 63;
    for (int g0 = tid >> 6; g0 < NCG; g0 += NW) {
        const int cg = __builtin_amdgcn_readfirstlane(g0);
        float acc[8];
        #pragma unroll
        for (int j=0;j<8;++j){ int c=cg*8+j; acc[j] = (c < NOUT) ? Bv[c] : 0.f; }
        {
            const float* xrow = &Xs[(long)lane*xp];
            const float* wp = &W[cg*8];
            #pragma unroll 4
            for (int k=0;k<K;++k){
                const float xv = xrow[k];
                const float4* w4 = reinterpret_cast<const float4*>(wp + (long)k*WPITCH);
                float4 a = w4[0], b = w4[1];
                acc[0]=fmaf(xv,a.x,acc[0]); acc[1]=fmaf(xv,a.y,acc[1]);
                acc[2]=fmaf(xv,a.z,acc[2]); acc[3]=fmaf(xv,a.w,acc[3]);
                acc[4]=fmaf(xv,b.x,acc[4]); acc[5]=fmaf(xv,b.y,acc[5]);
                acc[6]=fmaf(xv,b.z,acc[6]); acc[7]=fmaf(xv,b.w,acc[7]);
            }
        }
        {
            const float* xrow = &X2s[(long)lane*xp2];
            const float* wp = &W2[cg*8];
            #pragma unroll 4
            for (int k=0;k<K;++k){
                const float xv = xrow[k];
                const float4* w4 = reinterpret_cast<const float4*>(wp + (long)k*WPITCH);
                float4 a = w4[0], b = w4[1];
                acc[0]=fmaf(xv,a.x,acc[0]); acc[1]=fmaf(xv,a.y,acc[1]);
                acc[2]=fmaf(xv,a.z,acc[2]); acc[3]=fmaf(xv,a.w,acc[3]);
                acc[4]=fmaf(xv,b.x,acc[4]); acc[5]=fmaf(xv,b.y,acc[5]);
                acc[6]=fmaf(xv,b.z,acc[6]); acc[7]=fmaf(xv,b.w,acc[7]);
            }
        }
        #pragma unroll
        for (int j=0;j<8;++j){
            int c = cg*8 + j;
            if (c < NOUT) Y[(long)lane*ypitch + c] = acc[j];
        }
    }
    __syncthreads();
}

// ---------------- F1: nn1 encoder + gWs + gWh + |s|^2 ----------------
__global__ __launch_bounds__(256)
void f1_encoder(const float* __restrict__ x0, const float* __restrict__ wp,
                const float* n1W0,const float* n1b0,const float* n1W1,const float* n1b1,
                const float* n1b2, const float* gbs, const float* gbh,
                float* __restrict__ x12g, float* __restrict__ sg,
                float* __restrict__ sqg, float* __restrict__ hg /*pitch 32*/)
{
    __shared__ float A1[64*65], A2[64*65], Ss[64*9];
    const int tid = threadIdx.x;
    const long row0 = (long)blockIdx.x*64;
    lin8<12,64,64,true,256>(x0+row0*12,12, n1W0, n1b0, A1,65, tid);
    lin8<64,64,64,true,256>(A1,65, n1W1, n1b1, A2,65, tid);
    lin8<64,12,16,true,256>(A2,65, wp+PAD_OFF_N1W2, n1b2, A1,13, tid);
    for (int i=tid;i<64*12;i+=256){ int r=i/12,c=i-r*12; x12g[(row0+r)*12+c]=A1[r*13+c]; }
    lin8<12,8,16,false,256>(A1,13, wp+PAD_OFF_GWS, gbs, Ss,9, tid);
    lin8<12,22,32,false,256>(A1,13, wp+PAD_OFF_GWH, gbh, hg+row0*32,32, tid);
    if (tid < 64) {
        float acc = 0.f;
        #pragma unroll
        for (int k=0;k<8;++k){ float v=Ss[tid*9+k]; sg[(row0+tid)*8+k]=v; acc=fmaf(v,v,acc); }
        sqg[row0+tid] = acc;
    }
}

// ---------------- kNN (R8): 4 q/wave, 4 cand/lane, sorted-pair top-2 ----------------
template<int C>
__device__ __forceinline__ unsigned dpp_umin(unsigned x){
    unsigned y = (unsigned)__builtin_amdgcn_update_dpp((int)x, (int)x, C, 0xf, 0xf, false);
    return x < y ? x : y;
}
__device__ __forceinline__ unsigned wave_umin64(unsigned x){
    x = dpp_umin<0x111>(x);
    x = dpp_umin<0x112>(x);
    x = dpp_umin<0x114>(x);
    x = dpp_umin<0x118>(x);
    x = dpp_umin<0x142>(x);
    x = dpp_umin<0x143>(x);
    return x;   // lane 63 holds the wave min
}

#define KNN_WPB 4
#define QPW 4

__global__ __launch_bounds__(256)
void knn_kernel(const float* __restrict__ S, const float* __restrict__ SQ,
                int* __restrict__ idx_out, float* __restrict__ w_out, int N)
{
    __shared__ __align__(16) float tile[9*256];
    const int tid  = threadIdx.x;
    const int lane = tid & 63;
    const int wv   = tid >> 6;
    const int q0   = (blockIdx.x*KNN_WPB + wv)*QPW;
    const int qtile = q0 >> 8;

    float qa[QPW][8]; float sqq[QPW];
    #pragma unroll
    for (int qq=0; qq<QPW; ++qq) {
        const float4* qp = reinterpret_cast<const float4*>(&S[(long)(q0+qq)*8]);
        float4 a = qp[0], b = qp[1];
        qa[qq][0]=a.x; qa[qq][1]=a.y; qa[qq][2]=a.z; qa[qq][3]=a.w;
        qa[qq][4]=b.x; qa[qq][5]=b.y; qa[qq][6]=b.z; qa[qq][7]=b.w;
        sqq[qq] = SQ[q0+qq];
    }

    unsigned s0[QPW], s1[QPW];
    #pragma unroll
    for (int qq=0; qq<QPW; ++qq){ s0[qq]=0xFFFFFFFFu; s1[qq]=0xFFFFFFFFu; }

    const int NT = N >> 8;
    #pragma unroll 1
    for (int t = 0; t < NT; ++t) {
        __syncthreads();
        {
            const float4* cp = reinterpret_cast<const float4*>(&S[(long)(t*256 + tid)*8]);
            float4 a = cp[0], b = cp[1];
            tile[0*256+tid]=a.x; tile[1*256+tid]=a.y; tile[2*256+tid]=a.z; tile[3*256+tid]=a.w;
            tile[4*256+tid]=b.x; tile[5*256+tid]=b.y; tile[6*256+tid]=b.z; tile[7*256+tid]=b.w;
            tile[8*256+tid]=SQ[t*256 + tid];
        }
        __syncthreads();

        float dot[QPW][4];
        #pragma unroll
        for (int qq=0;qq<QPW;++qq){ dot[qq][0]=0.f; dot[qq][1]=0.f; dot[qq][2]=0.f; dot[qq][3]=0.f; }
        #pragma unroll
        for (int k=0;k<8;++k){
            float4 v = *reinterpret_cast<const float4*>(&tile[k*256 + lane*4]);
            #pragma unroll
            for (int qq=0;qq<QPW;++qq){
                dot[qq][0] = fmaf(qa[qq][k], v.x, dot[qq][0]);
                dot[qq][1] = fmaf(qa[qq][k], v.y, dot[qq][1]);
                dot[qq][2] = fmaf(qa[qq][k], v.z, dot[qq][2]);
                dot[qq][3] = fmaf(qa[qq][k], v.w, dot[qq][3]);
            }
        }
        float4 sc = *reinterpret_cast<const float4*>(&tile[8*256 + lane*4]);
        const float scv[4] = {sc.x, sc.y, sc.z, sc.w};

        if (t != qtile) {
            #pragma unroll
            for (int qq=0;qq<QPW;++qq){
                #pragma unroll
                for (int i=0;i<4;++i){
                    float d2 = fmaf(-2.f, dot[qq][i], sqq[qq] + scv[i]);
                    d2 = fmaxf(d2, 0.f);
                    unsigned key = (__float_as_uint(d2) & 0xFFFFFF00u) | (unsigned)((t<<2)|i);
                    unsigned lo = s0[qq] < key ? s0[qq] : key;
                    unsigned hi = s0[qq] > key ? s0[qq] : key;
                    s0[qq] = lo;
                    s1[qq] = s1[qq] < hi ? s1[qq] : hi;
                }
            }
        } else {
            #pragma unroll
            for (int qq=0;qq<QPW;++qq){
                const int off = (q0+qq) - t*256;
                #pragma unroll
                for (int i=0;i<4;++i){
                    float d2 = fmaf(-2.f, dot[qq][i], sqq[qq] + scv[i]);
                    d2 = fmaxf(d2, 0.f);
                    unsigned key = (__float_as_uint(d2) & 0xFFFFFF00u) | (unsigned)((t<<2)|i);
                    if (lane*4 + i == off) key = 0xFFFFFFFFu;
                    unsigned lo = s0[qq] < key ? s0[qq] : key;
                    unsigned hi = s0[qq] > key ? s0[qq] : key;
                    s0[qq] = lo;
                    s1[qq] = s1[qq] < hi ? s1[qq] : hi;
                }
            }
        }
    }

    #pragma unroll
    for (int qq=0; qq<QPW; ++qq) {
        const int q = q0 + qq;
        unsigned savedK = 0; int savedC = 0;
        #pragma unroll 1
        for (int p=0; p<KNN; ++p) {
            unsigned red = wave_umin64(s0[qq]);
            unsigned gm = (unsigned)__builtin_amdgcn_readlane((int)red, 63);
            unsigned long long bal = __ballot(s0[qq] == gm);
            int owner = __ffsll((long long)bal) - 1;
            if (lane == owner) { s0[qq] = s1[qq]; s1[qq] = 0xFFFFFFFFu; }
            if (lane == p) { savedK = gm; savedC = owner; }
        }
        if (lane < KNN) {
            const int tl = (int)((savedK >> 2) & 0x3Fu);
            const int ii = (int)(savedK & 3u);
            const int c  = tl*256 + savedC*4 + ii;
            const float d2 = __uint_as_float(savedK & 0xFFFFFF00u);
            idx_out[(long)q*KNN + lane] = c;
            w_out[(long)q*KNN + lane]   = expf(-10.f * d2);
        }
    }
}

// ---------------- F2: GravNet aggregate + lin 56->64 ----------------
__global__ __launch_bounds__(256)
void f2_agg(const float* __restrict__ hg /*pitch 32*/, const int* __restrict__ idx,
            const float* __restrict__ wgt, const float* __restrict__ x12g,
            const float* gWo, const float* gbo, float* __restrict__ xg)
{
    __shared__ int   IDs[64*40];
    __shared__ float Wt[64*40];
    __shared__ float AGG[64*57];
    const int tid = threadIdx.x;
    const long row0 = (long)blockIdx.x*64;
    for (int i=tid;i<64*40;i+=256){ int r=i/40,k=i-r*40;
        IDs[i]=idx[(row0+r)*40+k]; Wt[i]=wgt[(row0+r)*40+k]; }
    for (int i=tid;i<64*12;i+=256){ int r=i/12,c=i-r*12; AGG[r*57+44+c]=x12g[(row0+r)*12+c]; }
    __syncthreads();
    {
        const int r = tid & 63, g = tid >> 6;
        const int f0 = g*8;
        const int nf = (f0 < 22) ? ((22-f0) < 8 ? (22-f0) : 8) : 0;
        float sm[8], mx[8];
        #pragma unroll
        for (int u=0;u<8;++u){ sm[u]=0.f; mx[u]=-INFINITY; }
        if (nf > 0) {
            #pragma unroll 1
            for (int k=0;k<40;++k){
                int j = IDs[r*40+k]; float wv = Wt[r*40+k];
                const float4* hp = reinterpret_cast<const float4*>(&hg[(long)j*32 + f0]);
                float4 h0 = hp[0], h1 = hp[1];
                float hv[8] = {h0.x,h0.y,h0.z,h0.w, h1.x,h1.y,h1.z,h1.w};
                #pragma unroll
                for (int u=0;u<8;++u){ float m = hv[u]*wv; sm[u]+=m; mx[u]=fmaxf(mx[u],m); }
            }
            #pragma unroll
            for (int u=0;u<8;++u) if (u<nf){ AGG[r*57+f0+u]=sm[u]*(1.f/40.f); AGG[r*57+22+f0+u]=mx[u]; }
        }
    }
    __syncthreads();
    lin8<56,64,64,false,256>(AGG,57, gWo, gbo, xg+row0*64,64, tid);
}

// ---------------- F3: GraphConv gather + dual linear ----------------
__global__ __launch_bounds__(256)
void f3_graphconv(const float* __restrict__ xgin, const int* __restrict__ idx,
                  const float* __restrict__ wgt,
                  const float* c2Wrel, const float* c2brel, const float* c2Wroot,
                  float* __restrict__ xc)
{
    __shared__ int   IDs[64*40];
    __shared__ float Wt[64*40];
    __shared__ float NB[64*65], XGs[64*65];
    const int tid = threadIdx.x;
    const long row0 = (long)blockIdx.x*64;
    for (int i=tid;i<64*40;i+=256){ int r=i/40,k=i-r*40;
        IDs[i]=idx[(row0+r)*40+k]; Wt[i]=wgt[(row0+r)*40+k]; }
    for (int i=tid;i<64*64;i+=256){ int r=i>>6,c=i&63; XGs[r*65+c]=xgin[(row0+r)*64+c]; }
    __syncthreads();
    {
        const int r = tid & 63, g = tid >> 6;
        float acc[16];
        #pragma unroll
        for (int j=0;j<16;++j) acc[j]=0.f;
        #pragma unroll 1
        for (int k=0;k<40;++k){
            int j = IDs[r*40+k]; float wv = Wt[r*40+k];
            const float4* xp = reinterpret_cast<const float4*>(&xgin[(long)j*64 + g*16]);
            #pragma unroll
            for (int m=0;m<4;++m){
                float4 v = xp[m];
                acc[4*m+0]=fmaf(v.x,wv,acc[4*m+0]);
                acc[4*m+1]=fmaf(v.y,wv,acc[4*m+1]);
                acc[4*m+2]=fmaf(v.z,wv,acc[4*m+2]);
                acc[4*m+3]=fmaf(v.w,wv,acc[4*m+3]);
            }
        }
        #pragma unroll
        for (int j=0;j<16;++j) NB[r*65 + g*16 + j] = acc[j];
    }
    __syncthreads();
    lin8_dual<64,64,64,256>(NB,65, XGs,65, c2Wrel,c2brel,c2Wroot, xc+row0*64,64, tid);
}

// ---------------- F45: MFMA fp16 heads ----------------
// X in LDS fp16, pitch 136 halves. WT[n][k] fp16 global, n padded to 128.
// 16 waves: wave wid -> m = wid&3 (row tile), nb = wid>>2; computes n tiles nb and nb+4.
// mfma_f32_16x16x32_f16: A lane: row=lane&15, k=8*(lane>>4)+j; B lane: col=lane&15,
// k=8*(lane>>4)+j; D: col=lane&15, row=(lane>>4)*4+reg.
template<int KP>
__device__ __forceinline__
void mfma_layer(const _Float16* __restrict__ Xl, const _Float16* __restrict__ WT,
                const float* __restrict__ Bv, _Float16* __restrict__ Yl, int tid)
{
    const int lane = tid & 63;
    const int wid  = __builtin_amdgcn_readfirstlane(tid >> 6);
    const int m   = wid & 3;
    const int nb  = wid >> 2;
    const int c15 = lane & 15;
    const int kg  = lane >> 4;
    f32x4 acc0 = {0.f,0.f,0.f,0.f};
    f32x4 acc1 = {0.f,0.f,0.f,0.f};
    const _Float16* xb = &Xl[(m*16 + c15)*136];
    const _Float16* w0 = &WT[(nb*16 + c15)*KP];
    const _Float16* w1 = &WT[((nb+4)*16 + c15)*KP];
    #pragma unroll
    for (int ks = 0; ks < KP/32; ++ks) {
        const int kb = kg*8 + ks*32;
        half8 a  = *reinterpret_cast<const half8*>(&xb[kb]);
        half8 b0 = *reinterpret_cast<const half8*>(&w0[kb]);
        half8 b1 = *reinterpret_cast<const half8*>(&w1[kb]);
        acc0 = __builtin_amdgcn_mfma_f32_16x16x32_f16(a, b0, acc0, 0, 0, 0);
        acc1 = __builtin_amdgcn_mfma_f32_16x16x32_f16(a, b1, acc1, 0, 0, 0);
    }
    const int drow = m*16 + kg*4;
    const int c0 = nb*16 + c15;
    const int c1 = (nb+4)*16 + c15;
    #pragma unroll
    for (int r = 0; r < 4; ++r) {
        float v0 = (c0 < 126) ? lrelu_f(acc0[r] + Bv[c0]) : 0.f;
        float v1 = (c1 < 126) ? lrelu_f(acc1[r] + Bv[c1]) : 0.f;
        Yl[(drow+r)*136 + c0] = (_Float16)v0;
        Yl[(drow+r)*136 + c1] = (_Float16)v1;
    }
    __syncthreads();
}

// final 126->6 fp32 from fp16 X (pitch 136), W padded pitch 16
__device__ __forceinline__
void lin_out6h(const _Float16* __restrict__ Xs, const float* __restrict__ Wp,
               const float* __restrict__ Bv, float* __restrict__ Y, int ypitch, int tid)
{
    if (tid < 64*6) {
        const int r = tid / 6, c = tid - r*6;
        float acc = Bv[c];
        const _Float16* xrow = &Xs[r*136];
        #pragma unroll 4
        for (int k=0;k<126;++k) acc = fmaf((float)xrow[k], Wp[k*16+c], acc);
        Y[(long)r*ypitch + c] = lrelu_f(acc);
    }
    __syncthreads();
}

__global__ __launch_bounds__(1024)
void f45_mfma(const float* __restrict__ xc, const float* __restrict__ x0,
              const float* __restrict__ wp, const _Float16* __restrict__ wt,
              const float* A_b0,const float* A_b1,const float* A_b2,const float* A_b3,
              const float* B_b0,const float* B_b1,const float* B_b2,const float* B_b3,
              float* __restrict__ outIds, float* __restrict__ outP4)
{
    __shared__ __align__(16) _Float16 bufA[64*136];
    __shared__ __align__(16) _Float16 bufB[64*136];
    __shared__ float IDS[64*6];
    const int tid = threadIdx.x;
    const long row0 = (long)blockIdx.x*64;
    // stage nn2 input: xc -> fp16 (KP=64, exact)
    for (int i=tid;i<64*64;i+=1024){ int r=i>>6,c=i&63;
        bufA[r*136+c] = (_Float16)xc[(row0+r)*64+c]; }
    __syncthreads();
    mfma_layer<64>(bufA, wt+T_N2W0, A_b0, bufB, tid);
    mfma_layer<128>(bufB, wt+T_N2W1, A_b1, bufA, tid);
    mfma_layer<128>(bufA, wt+T_N2W2, A_b2, bufB, tid);
    lin_out6h(bufB, wp+PAD_OFF_N2W3, A_b3, IDS, 6, tid);
    for (int i=tid;i<64*6;i+=1024){ int r=i/6,c=i-r*6; outIds[(row0+r)*6+c]=IDS[i]; }
    // stage nn3 input: [xc(64), ids(6), x0(12), pad] -> 96 cols
    for (int i=tid;i<64*96;i+=1024){
        int r=i/96, c=i-r*96;
        float v;
        if (c < 64)      v = xc[(row0+r)*64 + c];
        else if (c < 70) v = IDS[r*6 + (c-64)];
        else if (c < 82) v = x0[(row0+r)*12 + (c-70)];
        else             v = 0.f;
        bufA[r*136+c] = (_Float16)v;
    }
    __syncthreads();
    mfma_layer<96>(bufA, wt+T_N3W0, B_b0, bufB, tid);
    mfma_layer<128>(bufB, wt+T_N3W1, B_b1, bufA, tid);
    mfma_layer<128>(bufA, wt+T_N3W2, B_b2, bufB, tid);
    lin_out6h(bufB, wp+PAD_OFF_N3W3, B_b3, outP4+row0*6, 6, tid);
}

// ---------------- passthrough outputs ----------------
__global__ void copyout_kernel(const int* __restrict__ gid, const float* __restrict__ gy,
                               const int* __restrict__ cid, const float* __restrict__ cy,
                               float* __restrict__ out, int N)
{
    long i = (long)blockIdx.x*blockDim.x + threadIdx.x;
    long n = N;
    if (i < n)            out[12*n + i]         = (float)gid[i];
    else if (i < 7*n)     out[13*n + (i - n)]   = gy[i - n];
    else if (i < 8*n)     out[19*n + (i - 7*n)] = (float)cid[i - 7*n];
    else if (i < 14*n)    out[20*n + (i - 8*n)] = cy[i - 8*n];
}

extern "C" void kernel_launch(void* const* d_in, const int* in_sizes, int n_in,
                              void* d_out, int out_size, void* d_ws, size_t ws_size,
                              hipStream_t stream)
{
    const float* x0     = (const float*)d_in[0];
    const float* ygen   = (const float*)d_in[1];
    const float* ycand  = (const float*)d_in[2];
    const int*   ygenid = (const int*)d_in[3];
    const int*   ycandid= (const int*)d_in[4];
    const float* n1W0=(const float*)d_in[5],  *n1b0=(const float*)d_in[6];
    const float* n1W1=(const float*)d_in[7],  *n1b1=(const float*)d_in[8];
    const float* n1W2=(const float*)d_in[9],  *n1b2=(const float*)d_in[10];
    const float* gWs =(const float*)d_in[11], *gbs =(const float*)d_in[12];
    const float* gWh =(const float*)d_in[13], *gbh =(const float*)d_in[14];
    const float* gWo =(const float*)d_in[15], *gbo =(const float*)d_in[16];
    const float* c2Wrel=(const float*)d_in[17], *c2brel=(const float*)d_in[18];
    const float* c2Wroot=(const float*)d_in[19];
    const float* n2W0=(const float*)d_in[20], *n2b0=(const float*)d_in[21];
    const float* n2W1=(const float*)d_in[22], *n2b1=(const float*)d_in[23];
    const float* n2W2=(const float*)d_in[24], *n2b2=(const float*)d_in[25];
    const float* n2W3=(const float*)d_in[26], *n2b3=(const float*)d_in[27];
    const float* n3W0=(const float*)d_in[28], *n3b0=(const float*)d_in[29];
    const float* n3W1=(const float*)d_in[30], *n3b1=(const float*)d_in[31];
    const float* n3W2=(const float*)d_in[32], *n3b2=(const float*)d_in[33];
    const float* n3W3=(const float*)d_in[34], *n3b3=(const float*)d_in[35];

    const int N = in_sizes[0] / 12;      // 16384
    float* ws = (float*)d_ws;
    size_t off = 0;
    auto alloc = [&](size_t cnt){ float* p = ws + off; off += cnt; return p; };
    float* padw = alloc(PAD_TOTAL);
    _Float16* wt16 = (_Float16*)alloc((T_TOTAL+1)/2 + 8);
    float* x12  = alloc((size_t)N*12);
    float* s    = alloc((size_t)N*8);
    float* sq   = alloc((size_t)N);
    float* h    = alloc((size_t)N*32);
    int*   idxb = (int*)alloc((size_t)N*KNN);
    float* wb   = alloc((size_t)N*KNN);
    float* xg   = alloc((size_t)N*64);
    float* xc   = alloc((size_t)N*64);
    (void)ws_size; (void)n_in; (void)out_size;

    float* outF = (float*)d_out;
    const int GB = N / 64;               // 256 blocks

    pad_weights<<<(PAD_TOTAL+255)/256,256,0,stream>>>(gWs,gWh,n1W2,n2W3,n3W3, padw);
    pad_weights16<<<(T_TOTAL+255)/256,256,0,stream>>>(n2W0,n2W1,n2W2,n3W0,n3W1,n3W2, wt16);
    f1_encoder<<<GB,256,0,stream>>>(x0, padw, n1W0,n1b0, n1W1,n1b1, n1b2,
                                    gbs, gbh, x12, s, sq, h);
    knn_kernel<<<N/(KNN_WPB*QPW), 256, 0, stream>>>(s, sq, idxb, wb, N);
    f2_agg<<<GB,256,0,stream>>>(h, idxb, wb, x12, gWo, gbo, xg);
    f3_graphconv<<<GB,256,0,stream>>>(xg, idxb, wb, c2Wrel, c2brel, c2Wroot, xc);
    f45_mfma<<<GB,1024,0,stream>>>(xc, x0, padw, wt16,
                                   n2b0,n2b1,n2b2,n2b3, n3b0,n3b1,n3b2,n3b3,
                                   outF, outF + (size_t)N*6);
    copyout_kernel<<<(14*N+255)/256,256,0,stream>>>(ygenid, ygen, ycandid, ycand, outF, N);
}

// Round 11
// 260.190 us; speedup vs baseline: 1.4429x; 1.1203x over previous
//
#include <hip/hip_runtime.h>
#include <math.h>

static constexpr int KNN = 40;

__device__ __forceinline__ float lrelu_f(float v){ return v >= 0.f ? v : 0.5f*v; }

typedef _Float16 half8 __attribute__((ext_vector_type(8)));
typedef float    f32x4 __attribute__((ext_vector_type(4)));

// ---- fp32 padded-weight offsets (floats) ----
#define PAD_OFF_GWS   0        // 12x16  (8 cols)
#define PAD_OFF_GWH   192      // 12x32  (22 cols)
#define PAD_OFF_N1W2  576      // 64x16  (12 cols)
#define PAD_OFF_N2W3  1600     // 126x16 (6 cols)
#define PAD_OFF_N3W3  3616     // 126x16 (6 cols)
#define PAD_TOTAL     5632

// ---- fp16 transposed weight offsets (halves): WT[n][k], n padded to 128 ----
#define T_N2W0  0        // KP=64  (K=64)
#define T_N2W1  8192     // KP=128 (K=126)
#define T_N2W2  24576    // KP=128
#define T_N3W0  40960    // KP=96  (K=82)
#define T_N3W1  53248    // KP=128
#define T_N3W2  69632    // KP=128
#define T_TOTAL 86016

__global__ void pad_weights(const float* gWs,const float* gWh,const float* n1W2,
                            const float* n2W3,const float* n3W3,
                            float* __restrict__ wp)
{
    int i = blockIdx.x*blockDim.x + threadIdx.x;
    if (i >= PAD_TOTAL) return;
    const float* src; int cols, sh, off;
    if      (i < PAD_OFF_GWH)  { src=gWs;  cols=8;  sh=4; off=PAD_OFF_GWS;  }
    else if (i < PAD_OFF_N1W2) { src=gWh;  cols=22; sh=5; off=PAD_OFF_GWH;  }
    else if (i < PAD_OFF_N2W3) { src=n1W2; cols=12; sh=4; off=PAD_OFF_N1W2; }
    else if (i < PAD_OFF_N3W3) { src=n2W3; cols=6;  sh=4; off=PAD_OFF_N2W3; }
    else                       { src=n3W3; cols=6;  sh=4; off=PAD_OFF_N3W3; }
    int li = i - off;
    int r = li >> sh, c = li & ((1<<sh)-1);
    wp[i] = (c < cols) ? src[r*cols + c] : 0.f;
}

__global__ void pad_weights16(const float* n2W0,const float* n2W1,const float* n2W2,
                              const float* n3W0,const float* n3W1,const float* n3W2,
                              _Float16* __restrict__ wt)
{
    int i = blockIdx.x*blockDim.x + threadIdx.x;
    if (i >= T_TOTAL) return;
    const float* src; int KP, K, off;
    if      (i < T_N2W1) { src=n2W0; KP=64;  K=64;  off=T_N2W0; }
    else if (i < T_N2W2) { src=n2W1; KP=128; K=126; off=T_N2W1; }
    else if (i < T_N3W0) { src=n2W2; KP=128; K=126; off=T_N2W2; }
    else if (i < T_N3W1) { src=n3W0; KP=96;  K=82;  off=T_N3W0; }
    else if (i < T_N3W2) { src=n3W1; KP=128; K=126; off=T_N3W1; }
    else                 { src=n3W2; KP=128; K=126; off=T_N3W2; }
    int li = i - off;
    int n = li / KP, k = li - n*KP;
    float v = (n < 126 && k < K) ? src[k*126 + n] : 0.f;
    wt[i] = (_Float16)v;
}

// ---- lin8 (R8): wave owns 8 output cols -> wave-uniform W addresses ----
template<int K, int NOUT, int WPITCH, bool RELU, int NTH>
__device__ __forceinline__
void lin8(const float* __restrict__ Xs, int xpitch,
          const float* __restrict__ W, const float* __restrict__ Bv,
          float* __restrict__ Y, int ypitch, int tid)
{
    constexpr int NP  = ((NOUT+7)/8)*8;
    constexpr int NCG = NP/8;
    constexpr int NW  = NTH/64;
    const int lane = tid & 63;
    for (int g0 = tid >> 6; g0 < NCG; g0 += NW) {
        const int cg = __builtin_amdgcn_readfirstlane(g0);
        float acc[8];
        #pragma unroll
        for (int j=0;j<8;++j){ int c=cg*8+j; acc[j] = (c < NOUT) ? Bv[c] : 0.f; }
        const float* xrow = &Xs[(long)lane*xpitch];
        const float* wp = &W[cg*8];
        #pragma unroll 4
        for (int k=0;k<K;++k){
            const float xv = xrow[k];
            const float4* w4 = reinterpret_cast<const float4*>(wp + (long)k*WPITCH);
            float4 a = w4[0], b = w4[1];
            acc[0]=fmaf(xv,a.x,acc[0]); acc[1]=fmaf(xv,a.y,acc[1]);
            acc[2]=fmaf(xv,a.z,acc[2]); acc[3]=fmaf(xv,a.w,acc[3]);
            acc[4]=fmaf(xv,b.x,acc[4]); acc[5]=fmaf(xv,b.y,acc[5]);
            acc[6]=fmaf(xv,b.z,acc[6]); acc[7]=fmaf(xv,b.w,acc[7]);
        }
        #pragma unroll
        for (int j=0;j<8;++j){
            int c = cg*8 + j;
            if (c < NOUT){ float v = acc[j]; if (RELU) v = lrelu_f(v); Y[(long)lane*ypitch + c] = v; }
        }
    }
    __syncthreads();
}

template<int K, int NOUT, int WPITCH, int NTH>
__device__ __forceinline__
void lin8_dual(const float* __restrict__ Xs, int xp, const float* __restrict__ X2s, int xp2,
               const float* __restrict__ W, const float* __restrict__ Bv, const float* __restrict__ W2,
               float* __restrict__ Y, int ypitch, int tid)
{
    constexpr int NP  = ((NOUT+7)/8)*8;
    constexpr int NCG = NP/8;
    constexpr int NW  = NTH/64;
    const int lane = tid & 63;
    for (int g0 = tid >> 6; g0 < NCG; g0 += NW) {
        const int cg = __builtin_amdgcn_readfirstlane(g0);
        float acc[8];
        #pragma unroll
        for (int j=0;j<8;++j){ int c=cg*8+j; acc[j] = (c < NOUT) ? Bv[c] : 0.f; }
        {
            const float* xrow = &Xs[(long)lane*xp];
            const float* wp = &W[cg*8];
            #pragma unroll 4
            for (int k=0;k<K;++k){
                const float xv = xrow[k];
                const float4* w4 = reinterpret_cast<const float4*>(wp + (long)k*WPITCH);
                float4 a = w4[0], b = w4[1];
                acc[0]=fmaf(xv,a.x,acc[0]); acc[1]=fmaf(xv,a.y,acc[1]);
                acc[2]=fmaf(xv,a.z,acc[2]); acc[3]=fmaf(xv,a.w,acc[3]);
                acc[4]=fmaf(xv,b.x,acc[4]); acc[5]=fmaf(xv,b.y,acc[5]);
                acc[6]=fmaf(xv,b.z,acc[6]); acc[7]=fmaf(xv,b.w,acc[7]);
            }
        }
        {
            const float* xrow = &X2s[(long)lane*xp2];
            const float* wp = &W2[cg*8];
            #pragma unroll 4
            for (int k=0;k<K;++k){
                const float xv = xrow[k];
                const float4* w4 = reinterpret_cast<const float4*>(wp + (long)k*WPITCH);
                float4 a = w4[0], b = w4[1];
                acc[0]=fmaf(xv,a.x,acc[0]); acc[1]=fmaf(xv,a.y,acc[1]);
                acc[2]=fmaf(xv,a.z,acc[2]); acc[3]=fmaf(xv,a.w,acc[3]);
                acc[4]=fmaf(xv,b.x,acc[4]); acc[5]=fmaf(xv,b.y,acc[5]);
                acc[6]=fmaf(xv,b.z,acc[6]); acc[7]=fmaf(xv,b.w,acc[7]);
            }
        }
        #pragma unroll
        for (int j=0;j<8;++j){
            int c = cg*8 + j;
            if (c < NOUT) Y[(long)lane*ypitch + c] = acc[j];
        }
    }
    __syncthreads();
}

// ---------------- F1: nn1 encoder + gWs + gWh + |s|^2 ----------------
__global__ __launch_bounds__(256)
void f1_encoder(const float* __restrict__ x0, const float* __restrict__ wp,
                const float* n1W0,const float* n1b0,const float* n1W1,const float* n1b1,
                const float* n1b2, const float* gbs, const float* gbh,
                float* __restrict__ x12g, float* __restrict__ sg,
                float* __restrict__ sqg, float* __restrict__ hg /*pitch 32*/)
{
    __shared__ float A1[64*65], A2[64*65], Ss[64*9];
    const int tid = threadIdx.x;
    const long row0 = (long)blockIdx.x*64;
    lin8<12,64,64,true,256>(x0+row0*12,12, n1W0, n1b0, A1,65, tid);
    lin8<64,64,64,true,256>(A1,65, n1W1, n1b1, A2,65, tid);
    lin8<64,12,16,true,256>(A2,65, wp+PAD_OFF_N1W2, n1b2, A1,13, tid);
    for (int i=tid;i<64*12;i+=256){ int r=i/12,c=i-r*12; x12g[(row0+r)*12+c]=A1[r*13+c]; }
    lin8<12,8,16,false,256>(A1,13, wp+PAD_OFF_GWS, gbs, Ss,9, tid);
    lin8<12,22,32,false,256>(A1,13, wp+PAD_OFF_GWH, gbh, hg+row0*32,32, tid);
    if (tid < 64) {
        float acc = 0.f;
        #pragma unroll
        for (int k=0;k<8;++k){ float v=Ss[tid*9+k]; sg[(row0+tid)*8+k]=v; acc=fmaf(v,v,acc); }
        sqg[row0+tid] = acc;
    }
}

// ---------------- kNN (R8): 4 q/wave, 4 cand/lane, sorted-pair top-2 ----------------
template<int C>
__device__ __forceinline__ unsigned dpp_umin(unsigned x){
    unsigned y = (unsigned)__builtin_amdgcn_update_dpp((int)x, (int)x, C, 0xf, 0xf, false);
    return x < y ? x : y;
}
__device__ __forceinline__ unsigned wave_umin64(unsigned x){
    x = dpp_umin<0x111>(x);
    x = dpp_umin<0x112>(x);
    x = dpp_umin<0x114>(x);
    x = dpp_umin<0x118>(x);
    x = dpp_umin<0x142>(x);
    x = dpp_umin<0x143>(x);
    return x;   // lane 63 holds the wave min
}

#define KNN_WPB 4
#define QPW 4

__global__ __launch_bounds__(256)
void knn_kernel(const float* __restrict__ S, const float* __restrict__ SQ,
                int* __restrict__ idx_out, float* __restrict__ w_out, int N)
{
    __shared__ __align__(16) float tile[9*256];
    const int tid  = threadIdx.x;
    const int lane = tid & 63;
    const int wv   = tid >> 6;
    const int q0   = (blockIdx.x*KNN_WPB + wv)*QPW;
    const int qtile = q0 >> 8;

    float qa[QPW][8]; float sqq[QPW];
    #pragma unroll
    for (int qq=0; qq<QPW; ++qq) {
        const float4* qp = reinterpret_cast<const float4*>(&S[(long)(q0+qq)*8]);
        float4 a = qp[0], b = qp[1];
        qa[qq][0]=a.x; qa[qq][1]=a.y; qa[qq][2]=a.z; qa[qq][3]=a.w;
        qa[qq][4]=b.x; qa[qq][5]=b.y; qa[qq][6]=b.z; qa[qq][7]=b.w;
        sqq[qq] = SQ[q0+qq];
    }

    unsigned s0[QPW], s1[QPW];
    #pragma unroll
    for (int qq=0; qq<QPW; ++qq){ s0[qq]=0xFFFFFFFFu; s1[qq]=0xFFFFFFFFu; }

    const int NT = N >> 8;
    #pragma unroll 1
    for (int t = 0; t < NT; ++t) {
        __syncthreads();
        {
            const float4* cp = reinterpret_cast<const float4*>(&S[(long)(t*256 + tid)*8]);
            float4 a = cp[0], b = cp[1];
            tile[0*256+tid]=a.x; tile[1*256+tid]=a.y; tile[2*256+tid]=a.z; tile[3*256+tid]=a.w;
            tile[4*256+tid]=b.x; tile[5*256+tid]=b.y; tile[6*256+tid]=b.z; tile[7*256+tid]=b.w;
            tile[8*256+tid]=SQ[t*256 + tid];
        }
        __syncthreads();

        float dot[QPW][4];
        #pragma unroll
        for (int qq=0;qq<QPW;++qq){ dot[qq][0]=0.f; dot[qq][1]=0.f; dot[qq][2]=0.f; dot[qq][3]=0.f; }
        #pragma unroll
        for (int k=0;k<8;++k){
            float4 v = *reinterpret_cast<const float4*>(&tile[k*256 + lane*4]);
            #pragma unroll
            for (int qq=0;qq<QPW;++qq){
                dot[qq][0] = fmaf(qa[qq][k], v.x, dot[qq][0]);
                dot[qq][1] = fmaf(qa[qq][k], v.y, dot[qq][1]);
                dot[qq][2] = fmaf(qa[qq][k], v.z, dot[qq][2]);
                dot[qq][3] = fmaf(qa[qq][k], v.w, dot[qq][3]);
            }
        }
        float4 sc = *reinterpret_cast<const float4*>(&tile[8*256 + lane*4]);
        const float scv[4] = {sc.x, sc.y, sc.z, sc.w};

        if (t != qtile) {
            #pragma unroll
            for (int qq=0;qq<QPW;++qq){
                #pragma unroll
                for (int i=0;i<4;++i){
                    float d2 = fmaf(-2.f, dot[qq][i], sqq[qq] + scv[i]);
                    d2 = fmaxf(d2, 0.f);
                    unsigned key = (__float_as_uint(d2) & 0xFFFFFF00u) | (unsigned)((t<<2)|i);
                    unsigned lo = s0[qq] < key ? s0[qq] : key;
                    unsigned hi = s0[qq] > key ? s0[qq] : key;
                    s0[qq] = lo;
                    s1[qq] = s1[qq] < hi ? s1[qq] : hi;
                }
            }
        } else {
            #pragma unroll
            for (int qq=0;qq<QPW;++qq){
                const int off = (q0+qq) - t*256;
                #pragma unroll
                for (int i=0;i<4;++i){
                    float d2 = fmaf(-2.f, dot[qq][i], sqq[qq] + scv[i]);
                    d2 = fmaxf(d2, 0.f);
                    unsigned key = (__float_as_uint(d2) & 0xFFFFFF00u) | (unsigned)((t<<2)|i);
                    if (lane*4 + i == off) key = 0xFFFFFFFFu;
                    unsigned lo = s0[qq] < key ? s0[qq] : key;
                    unsigned hi = s0[qq] > key ? s0[qq] : key;
                    s0[qq] = lo;
                    s1[qq] = s1[qq] < hi ? s1[qq] : hi;
                }
            }
        }
    }

    #pragma unroll
    for (int qq=0; qq<QPW; ++qq) {
        const int q = q0 + qq;
        unsigned savedK = 0; int savedC = 0;
        #pragma unroll 1
        for (int p=0; p<KNN; ++p) {
            unsigned red = wave_umin64(s0[qq]);
            unsigned gm = (unsigned)__builtin_amdgcn_readlane((int)red, 63);
            unsigned long long bal = __ballot(s0[qq] == gm);
            int owner = __ffsll((long long)bal) - 1;
            if (lane == owner) { s0[qq] = s1[qq]; s1[qq] = 0xFFFFFFFFu; }
            if (lane == p) { savedK = gm; savedC = owner; }
        }
        if (lane < KNN) {
            const int tl = (int)((savedK >> 2) & 0x3Fu);
            const int ii = (int)(savedK & 3u);
            const int c  = tl*256 + savedC*4 + ii;
            const float d2 = __uint_as_float(savedK & 0xFFFFFF00u);
            idx_out[(long)q*KNN + lane] = c;
            w_out[(long)q*KNN + lane]   = expf(-10.f * d2);
        }
    }
}

// ---------------- F2: GravNet aggregate + lin 56->64 ----------------
__global__ __launch_bounds__(256)
void f2_agg(const float* __restrict__ hg /*pitch 32*/, const int* __restrict__ idx,
            const float* __restrict__ wgt, const float* __restrict__ x12g,
            const float* gWo, const float* gbo, float* __restrict__ xg)
{
    __shared__ int   IDs[64*40];
    __shared__ float Wt[64*40];
    __shared__ float AGG[64*57];
    const int tid = threadIdx.x;
    const long row0 = (long)blockIdx.x*64;
    for (int i=tid;i<64*40;i+=256){ int r=i/40,k=i-r*40;
        IDs[i]=idx[(row0+r)*40+k]; Wt[i]=wgt[(row0+r)*40+k]; }
    for (int i=tid;i<64*12;i+=256){ int r=i/12,c=i-r*12; AGG[r*57+44+c]=x12g[(row0+r)*12+c]; }
    __syncthreads();
    {
        const int r = tid & 63, g = tid >> 6;
        const int f0 = g*8;
        const int nf = (f0 < 22) ? ((22-f0) < 8 ? (22-f0) : 8) : 0;
        float sm[8], mx[8];
        #pragma unroll
        for (int u=0;u<8;++u){ sm[u]=0.f; mx[u]=-INFINITY; }
        if (nf > 0) {
            #pragma unroll 1
            for (int k=0;k<40;++k){
                int j = IDs[r*40+k]; float wv = Wt[r*40+k];
                const float4* hp = reinterpret_cast<const float4*>(&hg[(long)j*32 + f0]);
                float4 h0 = hp[0], h1 = hp[1];
                float hv[8] = {h0.x,h0.y,h0.z,h0.w, h1.x,h1.y,h1.z,h1.w};
                #pragma unroll
                for (int u=0;u<8;++u){ float m = hv[u]*wv; sm[u]+=m; mx[u]=fmaxf(mx[u],m); }
            }
            #pragma unroll
            for (int u=0;u<8;++u) if (u<nf){ AGG[r*57+f0+u]=sm[u]*(1.f/40.f); AGG[r*57+22+f0+u]=mx[u]; }
        }
    }
    __syncthreads();
    lin8<56,64,64,false,256>(AGG,57, gWo, gbo, xg+row0*64,64, tid);
}

// ---------------- F3: GraphConv gather + dual linear ----------------
__global__ __launch_bounds__(256)
void f3_graphconv(const float* __restrict__ xgin, const int* __restrict__ idx,
                  const float* __restrict__ wgt,
                  const float* c2Wrel, const float* c2brel, const float* c2Wroot,
                  float* __restrict__ xc)
{
    __shared__ int   IDs[64*40];
    __shared__ float Wt[64*40];
    __shared__ float NB[64*65], XGs[64*65];
    const int tid = threadIdx.x;
    const long row0 = (long)blockIdx.x*64;
    for (int i=tid;i<64*40;i+=256){ int r=i/40,k=i-r*40;
        IDs[i]=idx[(row0+r)*40+k]; Wt[i]=wgt[(row0+r)*40+k]; }
    for (int i=tid;i<64*64;i+=256){ int r=i>>6,c=i&63; XGs[r*65+c]=xgin[(row0+r)*64+c]; }
    __syncthreads();
    {
        const int r = tid & 63, g = tid >> 6;
        float acc[16];
        #pragma unroll
        for (int j=0;j<16;++j) acc[j]=0.f;
        #pragma unroll 1
        for (int k=0;k<40;++k){
            int j = IDs[r*40+k]; float wv = Wt[r*40+k];
            const float4* xp = reinterpret_cast<const float4*>(&xgin[(long)j*64 + g*16]);
            #pragma unroll
            for (int m=0;m<4;++m){
                float4 v = xp[m];
                acc[4*m+0]=fmaf(v.x,wv,acc[4*m+0]);
                acc[4*m+1]=fmaf(v.y,wv,acc[4*m+1]);
                acc[4*m+2]=fmaf(v.z,wv,acc[4*m+2]);
                acc[4*m+3]=fmaf(v.w,wv,acc[4*m+3]);
            }
        }
        #pragma unroll
        for (int j=0;j<16;++j) NB[r*65 + g*16 + j] = acc[j];
    }
    __syncthreads();
    lin8_dual<64,64,64,256>(NB,65, XGs,65, c2Wrel,c2brel,c2Wroot, xc+row0*64,64, tid);
}

// ---------------- F45: MFMA fp16 heads, weights staged in LDS ----------------
// X in LDS fp16, pitch 136 halves. WT[n][k] fp16 staged global->LDS per layer.
// 16 waves: wave wid -> m = wid&3 (row tile), nb = wid>>2; computes n tiles nb and nb+4.
template<int KP>
__device__ __forceinline__
void mfma_layer(const _Float16* __restrict__ Xl, const _Float16* __restrict__ WTg,
                _Float16* __restrict__ Wl,
                const float* __restrict__ Bv, _Float16* __restrict__ Yl, int tid)
{
    // stage W (128 x KP halves) into LDS: coalesced half8 chunks
    {
        const half8* src = reinterpret_cast<const half8*>(WTg);
        half8* dst = reinterpret_cast<half8*>(Wl);
        constexpr int CHUNKS = 128*KP/8;
        #pragma unroll
        for (int i = tid; i < CHUNKS; i += 1024) dst[i] = src[i];
    }
    __syncthreads();
    const int lane = tid & 63;
    const int wid  = __builtin_amdgcn_readfirstlane(tid >> 6);
    const int m   = wid & 3;
    const int nb  = wid >> 2;
    const int c15 = lane & 15;
    const int kg  = lane >> 4;
    f32x4 acc0 = {0.f,0.f,0.f,0.f};
    f32x4 acc1 = {0.f,0.f,0.f,0.f};
    const _Float16* xb = &Xl[(m*16 + c15)*136];
    const _Float16* w0 = &Wl[(nb*16 + c15)*KP];
    const _Float16* w1 = &Wl[((nb+4)*16 + c15)*KP];
    #pragma unroll
    for (int ks = 0; ks < KP/32; ++ks) {
        const int kb = kg*8 + ks*32;
        half8 a  = *reinterpret_cast<const half8*>(&xb[kb]);
        half8 b0 = *reinterpret_cast<const half8*>(&w0[kb]);
        half8 b1 = *reinterpret_cast<const half8*>(&w1[kb]);
        acc0 = __builtin_amdgcn_mfma_f32_16x16x32_f16(a, b0, acc0, 0, 0, 0);
        acc1 = __builtin_amdgcn_mfma_f32_16x16x32_f16(a, b1, acc1, 0, 0, 0);
    }
    const int drow = m*16 + kg*4;
    const int c0 = nb*16 + c15;
    const int c1 = (nb+4)*16 + c15;
    #pragma unroll
    for (int r = 0; r < 4; ++r) {
        float v0 = (c0 < 126) ? lrelu_f(acc0[r] + Bv[c0]) : 0.f;
        float v1 = (c1 < 126) ? lrelu_f(acc1[r] + Bv[c1]) : 0.f;
        Yl[(drow+r)*136 + c0] = (_Float16)v0;
        Yl[(drow+r)*136 + c1] = (_Float16)v1;
    }
    __syncthreads();
}

// final 126->6 fp32 from fp16 X (pitch 136); W staged to LDS as [126][8]
__device__ __forceinline__
void lin_out6h(const _Float16* __restrict__ Xs, const float* __restrict__ Wp,
               float* __restrict__ Wl6, const float* __restrict__ Bv,
               float* __restrict__ Y, int ypitch, int tid)
{
    for (int i = tid; i < 126*8; i += 1024) {
        int k = i >> 3, c = i & 7;
        Wl6[i] = Wp[k*16 + c];
    }
    __syncthreads();
    if (tid < 64*6) {
        const int r = tid / 6, c = tid - r*6;
        float acc = Bv[c];
        const _Float16* xrow = &Xs[r*136];
        #pragma unroll 4
        for (int k=0;k<126;++k) acc = fmaf((float)xrow[k], Wl6[k*8+c], acc);
        Y[(long)r*ypitch + c] = lrelu_f(acc);
    }
    __syncthreads();
}

__global__ __launch_bounds__(1024)
void f45_mfma(const float* __restrict__ xc, const float* __restrict__ x0,
              const float* __restrict__ wp, const _Float16* __restrict__ wt,
              const float* A_b0,const float* A_b1,const float* A_b2,const float* A_b3,
              const float* B_b0,const float* B_b1,const float* B_b2,const float* B_b3,
              float* __restrict__ outIds, float* __restrict__ outP4)
{
    __shared__ __align__(16) _Float16 bufA[64*136];
    __shared__ __align__(16) _Float16 bufB[64*136];
    __shared__ __align__(16) _Float16 Wl[128*128];   // 32KB layer-weight stage
    __shared__ float IDS[64*6];
    const int tid = threadIdx.x;
    const long row0 = (long)blockIdx.x*64;
    // stage nn2 input: xc -> fp16 (KP=64, exact)
    for (int i=tid;i<64*64;i+=1024){ int r=i>>6,c=i&63;
        bufA[r*136+c] = (_Float16)xc[(row0+r)*64+c]; }
    __syncthreads();
    mfma_layer<64>(bufA, wt+T_N2W0, Wl, A_b0, bufB, tid);
    mfma_layer<128>(bufB, wt+T_N2W1, Wl, A_b1, bufA, tid);
    mfma_layer<128>(bufA, wt+T_N2W2, Wl, A_b2, bufB, tid);
    lin_out6h(bufB, wp+PAD_OFF_N2W3, (float*)Wl, A_b3, IDS, 6, tid);
    for (int i=tid;i<64*6;i+=1024){ int r=i/6,c=i-r*6; outIds[(row0+r)*6+c]=IDS[i]; }
    // stage nn3 input: [xc(64), ids(6), x0(12), pad] -> 96 cols
    for (int i=tid;i<64*96;i+=1024){
        int r=i/96, c=i-r*96;
        float v;
        if (c < 64)      v = xc[(row0+r)*64 + c];
        else if (c < 70) v = IDS[r*6 + (c-64)];
        else if (c < 82) v = x0[(row0+r)*12 + (c-70)];
        else             v = 0.f;
        bufA[r*136+c] = (_Float16)v;
    }
    __syncthreads();
    mfma_layer<96>(bufA, wt+T_N3W0, Wl, B_b0, bufB, tid);
    mfma_layer<128>(bufB, wt+T_N3W1, Wl, B_b1, bufA, tid);
    mfma_layer<128>(bufA, wt+T_N3W2, Wl, B_b2, bufB, tid);
    lin_out6h(bufB, wp+PAD_OFF_N3W3, (float*)Wl, B_b3, outP4+row0*6, 6, tid);
}

// ---------------- passthrough outputs ----------------
__global__ void copyout_kernel(const int* __restrict__ gid, const float* __restrict__ gy,
                               const int* __restrict__ cid, const float* __restrict__ cy,
                               float* __restrict__ out, int N)
{
    long i = (long)blockIdx.x*blockDim.x + threadIdx.x;
    long n = N;
    if (i < n)            out[12*n + i]         = (float)gid[i];
    else if (i < 7*n)     out[13*n + (i - n)]   = gy[i - n];
    else if (i < 8*n)     out[19*n + (i - 7*n)] = (float)cid[i - 7*n];
    else if (i < 14*n)    out[20*n + (i - 8*n)] = cy[i - 8*n];
}

extern "C" void kernel_launch(void* const* d_in, const int* in_sizes, int n_in,
                              void* d_out, int out_size, void* d_ws, size_t ws_size,
                              hipStream_t stream)
{
    const float* x0     = (const float*)d_in[0];
    const float* ygen   = (const float*)d_in[1];
    const float* ycand  = (const float*)d_in[2];
    const int*   ygenid = (const int*)d_in[3];
    const int*   ycandid= (const int*)d_in[4];
    const float* n1W0=(const float*)d_in[5],  *n1b0=(const float*)d_in[6];
    const float* n1W1=(const float*)d_in[7],  *n1b1=(const float*)d_in[8];
    const float* n1W2=(const float*)d_in[9],  *n1b2=(const float*)d_in[10];
    const float* gWs =(const float*)d_in[11], *gbs =(const float*)d_in[12];
    const float* gWh =(const float*)d_in[13], *gbh =(const float*)d_in[14];
    const float* gWo =(const float*)d_in[15], *gbo =(const float*)d_in[16];
    const float* c2Wrel=(const float*)d_in[17], *c2brel=(const float*)d_in[18];
    const float* c2Wroot=(const float*)d_in[19];
    const float* n2W0=(const float*)d_in[20], *n2b0=(const float*)d_in[21];
    const float* n2W1=(const float*)d_in[22], *n2b1=(const float*)d_in[23];
    const float* n2W2=(const float*)d_in[24], *n2b2=(const float*)d_in[25];
    const float* n2W3=(const float*)d_in[26], *n2b3=(const float*)d_in[27];
    const float* n3W0=(const float*)d_in[28], *n3b0=(const float*)d_in[29];
    const float* n3W1=(const float*)d_in[30], *n3b1=(const float*)d_in[31];
    const float* n3W2=(const float*)d_in[32], *n3b2=(const float*)d_in[33];
    const float* n3W3=(const float*)d_in[34], *n3b3=(const float*)d_in[35];

    const int N = in_sizes[0] / 12;      // 16384
    float* ws = (float*)d_ws;
    size_t off = 0;
    auto alloc = [&](size_t cnt){ float* p = ws + off; off += cnt; return p; };
    float* padw = alloc(PAD_TOTAL);
    _Float16* wt16 = (_Float16*)alloc((T_TOTAL+1)/2 + 8);
    float* x12  = alloc((size_t)N*12);
    float* s    = alloc((size_t)N*8);
    float* sq   = alloc((size_t)N);
    float* h    = alloc((size_t)N*32);
    int*   idxb = (int*)alloc((size_t)N*KNN);
    float* wb   = alloc((size_t)N*KNN);
    float* xg   = alloc((size_t)N*64);
    float* xc   = alloc((size_t)N*64);
    (void)ws_size; (void)n_in; (void)out_size;

    float* outF = (float*)d_out;
    const int GB = N / 64;               // 256 blocks

    pad_weights<<<(PAD_TOTAL+255)/256,256,0,stream>>>(gWs,gWh,n1W2,n2W3,n3W3, padw);
    pad_weights16<<<(T_TOTAL+255)/256,256,0,stream>>>(n2W0,n2W1,n2W2,n3W0,n3W1,n3W2, wt16);
    f1_encoder<<<GB,256,0,stream>>>(x0, padw, n1W0,n1b0, n1W1,n1b1, n1b2,
                                    gbs, gbh, x12, s, sq, h);
    knn_kernel<<<N/(KNN_WPB*QPW), 256, 0, stream>>>(s, sq, idxb, wb, N);
    f2_agg<<<GB,256,0,stream>>>(h, idxb, wb, x12, gWo, gbo, xg);
    f3_graphconv<<<GB,256,0,stream>>>(xg, idxb, wb, c2Wrel, c2brel, c2Wroot, xc);
    f45_mfma<<<GB,1024,0,stream>>>(xc, x0, padw, wt16,
                                   n2b0,n2b1,n2b2,n2b3, n3b0,n3b1,n3b2,n3b3,
                                   outF, outF + (size_t)N*6);
    copyout_kernel<<<(14*N+255)/256,256,0,stream>>>(ygenid, ygen, ycandid, ycand, outF, N);
}